// Round 14
// baseline (184.502 us; speedup 1.0000x reference)
//
#include <hip/hip_runtime.h>
#include <hip/hip_bf16.h>
#include <math.h>

#define N_NODES 4096
#define FDIM 512            // K of both GEMMs (F_in = H*D = 512)
#define D 64
#define H 8
#define NWORDS (N_NODES / 64)
#define S1 4                // layer-1 j-slabs  (32 rb x 8 h x 4 = 1024 blocks)
#define S2 16               // layer-2 j-slabs  (32 rb x 16 = 512 blocks)

typedef __attribute__((ext_vector_type(8))) short bf16x8;      // raw 16B of halfwords
typedef __attribute__((ext_vector_type(4))) float f32x4;
typedef __attribute__((ext_vector_type(8))) _Float16 f16x8;    // MFMA f16 operand
typedef __attribute__((ext_vector_type(2))) _Float16 f16x2;    // packed-pair math
typedef __attribute__((ext_vector_type(4))) unsigned int u32x4;

__device__ inline short f2h(float x) {                         // f32->f16 RNE
    _Float16 h = (_Float16)x;
    return __builtin_bit_cast(short, h);
}
__device__ inline float h2f(unsigned short u) {
    return (float)__builtin_bit_cast(_Float16, u);
}
__device__ inline f16x2 bcH(unsigned int u) { return __builtin_bit_cast(f16x2, u); }

__device__ inline int sext_bit(unsigned int v, int j) {        // all-ones iff bit j set
#if defined(__has_builtin) && __has_builtin(__builtin_amdgcn_sbfe)
    return __builtin_amdgcn_sbfe((int)v, j, 1);
#else
    return ((int)(v << (31 - j))) >> 31;
#endif
}

// monotonic float<->uint encoding so unsigned atomicMax == float max
__device__ inline unsigned fenc(float f) {
    unsigned u = __builtin_bit_cast(unsigned, f);
    return (u & 0x80000000u) ? ~u : (u | 0x80000000u);
}
__device__ inline float fdec(unsigned e) {
    unsigned u = (e & 0x80000000u) ? (e & 0x7FFFFFFFu) : ~e;
    return __builtin_bit_cast(float, u);
}

// async global->LDS 16B copy (DMA). LDS dst must be wave-uniform base + lane*16.
__device__ inline void gl2lds16(const void* g, void* l) {
#if defined(__has_builtin) && __has_builtin(__builtin_amdgcn_global_load_lds)
    __builtin_amdgcn_global_load_lds(
        (const __attribute__((address_space(1))) unsigned int*)g,
        (__attribute__((address_space(3))) unsigned int*)l, 16, 0, 0);
#else
    *(uint4*)l = *(const uint4*)g;
#endif
}

// ---------------------------------------------------------------- fused preprocessing (proven R0-R3)
#define NB_BITS (N_NODES * N_NODES / 2048)
#define NB_X    (N_NODES * FDIM / 1024)
#define NB_W    (H * FDIM * D / 256)
#define NB_WO   (FDIM * D / 256)
__global__ void k_pre(const int* __restrict__ adj, const float* __restrict__ x,
                      const float* __restrict__ W, const float* __restrict__ Wo,
                      unsigned int* __restrict__ bits32, short* __restrict__ Xbf,
                      short* __restrict__ WF, short* __restrict__ WoF,
                      float* __restrict__ cm1, float* __restrict__ cm2,
                      unsigned* __restrict__ gmaxe1, unsigned* __restrict__ gmaxe2) {
    const int b = blockIdx.x, t = threadIdx.x;
    if (b == 0) {
        for (int i = t; i < H * D; i += 256) cm1[i] = 0.f;
        if (t < D) cm2[t] = 0.f;
        if (t < H) gmaxe1[t] = 0u;
        if (t == 0) gmaxe2[0] = 0u;
        return;
    }
    if (b < 1 + NB_BITS) {
        const int tid  = (b - 1) * 256 + t;     // one byte (8 adj) per thread
        const size_t e0 = (size_t)tid * 8;
        int4 a0 = *(const int4*)&adj[e0];
        int4 a1 = *(const int4*)&adj[e0 + 4];
        unsigned by = (unsigned)(a0.x != 0)       | ((unsigned)(a0.y != 0) << 1)
                    | ((unsigned)(a0.z != 0) << 2) | ((unsigned)(a0.w != 0) << 3)
                    | ((unsigned)(a1.x != 0) << 4) | ((unsigned)(a1.y != 0) << 5)
                    | ((unsigned)(a1.z != 0) << 6) | ((unsigned)(a1.w != 0) << 7);
        unsigned v = by | (__shfl_xor((int)by, 1) << 8);
        v = v | ((unsigned)__shfl_xor((int)v, 2) << 16);
        if ((t & 3) == 0) bits32[tid >> 2] = v;
        return;
    }
    if (b < 1 + NB_BITS + NB_X) {
        const size_t i4 = ((size_t)(b - 1 - NB_BITS) * 256 + t) * 4;
        float4 v = *(const float4*)&x[i4];
        ushort4 o;
        o.x = (unsigned short)f2h(v.x); o.y = (unsigned short)f2h(v.y);
        o.z = (unsigned short)f2h(v.z); o.w = (unsigned short)f2h(v.w);
        *(ushort4*)&Xbf[i4] = o;
        return;
    }
    if (b < 1 + NB_BITS + NB_X + NB_W) {
        const size_t idx = (size_t)(b - 1 - NB_BITS - NB_X) * 256 + t;   // (h*512+k)*64+d
        const int d = idx & 63;
        const int k = (int)(idx >> 6) & 511;
        const int h = (int)(idx >> 15);
        WF[(((size_t)h * 64 + (k >> 3)) * 64 + d) * 8 + (k & 7)] = f2h(W[idx]);
        return;
    }
    {
        const size_t idx = (size_t)(b - 1 - NB_BITS - NB_X - NB_W) * 256 + t;  // k*64+d
        const int d = idx & 63;
        const int k = (int)(idx >> 6);
        WoF[(((size_t)(k >> 3)) * 64 + d) * 8 + (k & 7)] = f2h(Wo[idx]);
    }
}

// ---------------------------------------------------------------- MFMA GEMM layer-1 (proven R0-R3, 256 thr)
__global__ void __launch_bounds__(256) k_gemm(
    const short* __restrict__ Xbf, const short* __restrict__ WF,
    const float* __restrict__ av, const float* __restrict__ bv,
    short* __restrict__ WBout, float* __restrict__ fs, float* __restrict__ fd,
    unsigned* __restrict__ gmaxe, float* __restrict__ cm) {
    const int h  = blockIdx.y;
    const int i0 = blockIdx.x * 64;
    const int t = threadIdx.x, w = t >> 6, lane = t & 63;
    const int li = lane & 15, quad = lane >> 4, k0 = quad * 8;
    const int row_a = i0 + w * 16 + li;
    const short* __restrict__ Xr  = Xbf + (size_t)row_a * FDIM;
    const short* __restrict__ WFh = WF + (size_t)h * 64 * D * 8;

    f32x4 c0 = {0.f, 0.f, 0.f, 0.f}, c1 = c0, c2 = c0, c3 = c0;
    #pragma unroll 4
    for (int kt = 0; kt < FDIM; kt += 32) {
        f16x8 a = __builtin_bit_cast(f16x8, *(const bf16x8*)&Xr[kt + k0]);
        const short* bb = WFh + (size_t)((kt >> 3) + quad) * (D * 8) + li * 8;
        f16x8 b0 = __builtin_bit_cast(f16x8, *(const bf16x8*)(bb));
        f16x8 b1 = __builtin_bit_cast(f16x8, *(const bf16x8*)(bb + 128));
        f16x8 b2 = __builtin_bit_cast(f16x8, *(const bf16x8*)(bb + 256));
        f16x8 b3 = __builtin_bit_cast(f16x8, *(const bf16x8*)(bb + 384));
        c0 = __builtin_amdgcn_mfma_f32_16x16x32_f16(a, b0, c0, 0, 0, 0);
        c1 = __builtin_amdgcn_mfma_f32_16x16x32_f16(a, b1, c1, 0, 0, 0);
        c2 = __builtin_amdgcn_mfma_f32_16x16x32_f16(a, b2, c2, 0, 0, 0);
        c3 = __builtin_amdgcn_mfma_f32_16x16x32_f16(a, b3, c3, 0, 0, 0);
    }
    float av4[4], bv4[4];
    #pragma unroll
    for (int t4 = 0; t4 < 4; ++t4) {
        av4[t4] = av[h * D + t4 * 16 + li];
        bv4[t4] = bv[h * D + t4 * 16 + li];
    }
    float tiles[4][4];
    #pragma unroll
    for (int r = 0; r < 4; ++r) { tiles[0][r] = c0[r]; tiles[1][r] = c1[r]; tiles[2][r] = c2[r]; tiles[3][r] = c3[r]; }

    __shared__ float csum[4][64];
    __shared__ float red[4];
    float fdmax = -INFINITY;
    float s4[4] = {0.f, 0.f, 0.f, 0.f};

    #pragma unroll
    for (int r = 0; r < 4; ++r) {
        const int row = i0 + w * 16 + quad * 4 + r;
        float pa = 0.f, pb = 0.f;
        #pragma unroll
        for (int t4 = 0; t4 < 4; ++t4) {
            const float v = tiles[t4][r];
            const int d = t4 * 16 + li;
            WBout[((size_t)h * (N_NODES / 8) + (row >> 3)) * (D * 8) + d * 8 + (row & 7)] = f2h(v);
            pa += v * av4[t4];
            pb += v * bv4[t4];
            s4[t4] += v;
        }
        #pragma unroll
        for (int off = 1; off < 16; off <<= 1) {
            pa += __shfl_xor(pa, off);
            pb += __shfl_xor(pb, off);
        }
        if (li == 0) {
            fs[(size_t)h * N_NODES + row] = pa;
            fd[(size_t)h * N_NODES + row] = pb;
        }
        fdmax = fmaxf(fdmax, pb);
    }
    fdmax = fmaxf(fdmax, __shfl_xor(fdmax, 16));
    fdmax = fmaxf(fdmax, __shfl_xor(fdmax, 32));
    if (lane == 0) red[w] = fdmax;
    #pragma unroll
    for (int t4 = 0; t4 < 4; ++t4) {
        s4[t4] += __shfl_xor(s4[t4], 16);
        s4[t4] += __shfl_xor(s4[t4], 32);
    }
    if (quad == 0)
        #pragma unroll
        for (int t4 = 0; t4 < 4; ++t4) csum[w][t4 * 16 + li] = s4[t4];
    __syncthreads();
    if (t == 0)
        atomicMax(gmaxe + h, fenc(fmaxf(fmaxf(red[0], red[1]), fmaxf(red[2], red[3]))));
    if (t < 64)
        atomicAdd(&cm[h * D + t],
                  (csum[0][t] + csum[1][t] + csum[2][t] + csum[3][t]) * (1.f / (float)N_NODES));
}

// ---------------------------------------------------------------- MFMA attention aggregation (R11 LUT + XCD swizzle)
// 1D grid = 32 rb x nh heads x nslab slabs. XCD-aware remap (T1): hardware
// round-robins consecutive blockIdx across the 8 XCDs; blocks with the same
// (h,slab) read the SAME B j-panel, so we assign each XCD whole (h,slab)
// groups: xcd = b&7 owns groups [xcd*gpx, (xcd+1)*gpx), 32 rb each. Working
// set per XCD-L2 drops from all-heads (4 MB, thrashes) to gpx panels (2 MB).
// Bijective: grid = 8 * gpx * 32 exactly.
__global__ void __launch_bounds__(128, 2) k_accum(
    const unsigned int* __restrict__ bits32,
    const short* __restrict__ WB,
    const float* __restrict__ fsb, const float* __restrict__ fdb,
    const unsigned* __restrict__ gmaxe,
    short* __restrict__ num, float* __restrict__ den, int kslab, int nh) {

    __shared__ __align__(16) short Bt[2][16 * 64 * 8];   // 32 KB
    __shared__ __align__(16) short Et[2][128];           // f16 exp(fd-gm), per-tile
    __shared__ __align__(16) short Gt[2][128];           // f16 exp(0.2*(fd-gm))
    __shared__ __align__(16) uint4 MLUT[256];            // 4 KB: byte -> 4 pair-masks

    // ---- XCD-aware block remap
    const int b    = blockIdx.x;
    const int gpx  = (int)gridDim.x >> 8;      // groups per XCD = (grid/32)/8
    const int xcd  = b & 7, idx = b >> 3;
    const int g    = xcd * gpx + (idx >> 5);   // (h,slab) group
    const int rb   = idx & 31;
    const int h    = g % nh;
    const int slab = g / nh;

    const int i0 = rb * 128;
    const int t = threadIdx.x, w = t >> 6, lane = t & 63;
    const int li = lane & 15, quad = lane >> 4, k0 = quad * 8;
    const size_t ho = (size_t)h * N_NODES;
    const float  gm = fdec(gmaxe[h]);
    const float* __restrict__ fd = fdb + ho;
    const short* __restrict__ Bh = WB + (size_t)h * (N_NODES / 8) * D * 8;

    const int k_beg = slab * kslab;
    const int ntile = kslab / 128;

    auto stage = [&](int buf, int jtile) {
        const short* src = Bh + (size_t)(jtile >> 3) * (D * 8);
        #pragma unroll
        for (int p = 0; p < 8; ++p)
            gl2lds16(src + (size_t)(p * 128 + t) * 8, &Bt[buf][(p * 128 + t) * 8]);
    };
    auto stage_eg = [&](int buf, int jtile) {            // 128 j per tile, 1/thread
        const float f = fd[jtile + t];
        Et[buf][t] = f2h(__expf(f - gm));
        Gt[buf][t] = f2h(__expf(0.2f * (f - gm)));
    };

    int bito[4];
    #pragma unroll
    for (int f = 0; f < 4; ++f)
        bito[f] = (i0 + w * 64 + f * 16 + li) * (NWORDS * 2);
    stage(0, k_beg);
    stage_eg(0, k_beg);
    #pragma unroll
    for (int e = t; e < 256; e += 128) {                 // fill mask LUT (once)
        uint4 m;
        m.x = ((unsigned)sext_bit(e, 0) & 0x0000FFFFu) | ((unsigned)sext_bit(e, 1) & 0xFFFF0000u);
        m.y = ((unsigned)sext_bit(e, 2) & 0x0000FFFFu) | ((unsigned)sext_bit(e, 3) & 0xFFFF0000u);
        m.z = ((unsigned)sext_bit(e, 4) & 0x0000FFFFu) | ((unsigned)sext_bit(e, 5) & 0xFFFF0000u);
        m.w = ((unsigned)sext_bit(e, 6) & 0x0000FFFFu) | ((unsigned)sext_bit(e, 7) & 0xFFFF0000u);
        MLUT[e] = m;
    }
    f16x2 Rp[4];
    #pragma unroll
    for (int f = 0; f < 4; ++f) {
        const float rv = __expf(-0.8f * (fsb[ho + i0 + w * 64 + f * 16 + li] + gm));
        const _Float16 rh = (_Float16)rv;
        Rp[f] = (f16x2){rh, rh};
    }

    f32x4 acc[4][4], c5[4];
    #pragma unroll
    for (int f = 0; f < 4; ++f) {
        #pragma unroll
        for (int q = 0; q < 4; ++q) acc[f][q] = (f32x4){0.f, 0.f, 0.f, 0.f};
        c5[f] = (f32x4){0.f, 0.f, 0.f, 0.f};
    }
    bf16x8 ones_;
    #pragma unroll
    for (int j = 0; j < 8; ++j) ones_[j] = (short)0x3C00;    // f16 1.0
    const f16x8 ones = __builtin_bit_cast(f16x8, ones_);

    __syncthreads();   // stage(0) + EG(0) + LUT landed

    for (int tile = 0; tile < ntile; ++tile) {
        const int jt = k_beg + tile * 128;
        if (tile + 1 < ntile) {
            stage((tile + 1) & 1, jt + 128);
            stage_eg((tile + 1) & 1, jt + 128);
        }

        uint4 bw[4];
        #pragma unroll
        for (int f = 0; f < 4; ++f)
            bw[f] = *(const uint4*)&bits32[(size_t)bito[f] + (jt >> 5)];

        const short* Bl = Bt[tile & 1];
        const short* Ee = Et[tile & 1];
        const short* Gg = Gt[tile & 1];
        #pragma unroll
        for (int s = 0; s < 4; ++s) {
            const uint4 Eu = *(const uint4*)&Ee[s * 32 + k0];   // 8 f16 (broadcast per quad)
            const uint4 Gu = *(const uint4*)&Gg[s * 32 + k0];
            f16x2 Ep[4] = {bcH(Eu.x), bcH(Eu.y), bcH(Eu.z), bcH(Eu.w)};
            f16x2 Gp[4] = {bcH(Gu.x), bcH(Gu.y), bcH(Gu.z), bcH(Gu.w)};
            const short* bb = Bl + (size_t)((s * 4 + quad) * 64 + li) * 8;
            f16x8 b0 = __builtin_bit_cast(f16x8, *(const bf16x8*)(bb));
            f16x8 b1 = __builtin_bit_cast(f16x8, *(const bf16x8*)(bb + 128));
            f16x8 b2 = __builtin_bit_cast(f16x8, *(const bf16x8*)(bb + 256));
            f16x8 b3 = __builtin_bit_cast(f16x8, *(const bf16x8*)(bb + 384));
            #pragma unroll
            for (int f = 0; f < 4; ++f) {
                const unsigned int wsel = (s == 0) ? bw[f].x : (s == 1) ? bw[f].y
                                        : (s == 2) ? bw[f].z : bw[f].w;
                const unsigned int byt = (wsel >> k0) & 0xFFu;
                const uint4 mq = MLUT[byt];                     // ds_read_b128
                u32x4 au;
                {
                    const f16x2 p0 = __builtin_elementwise_max(Ep[0], Gp[0] * Rp[f]);
                    const f16x2 p1 = __builtin_elementwise_max(Ep[1], Gp[1] * Rp[f]);
                    const f16x2 p2 = __builtin_elementwise_max(Ep[2], Gp[2] * Rp[f]);
                    const f16x2 p3 = __builtin_elementwise_max(Ep[3], Gp[3] * Rp[f]);
                    au[0] = __builtin_bit_cast(unsigned, p0) & mq.x;
                    au[1] = __builtin_bit_cast(unsigned, p1) & mq.y;
                    au[2] = __builtin_bit_cast(unsigned, p2) & mq.z;
                    au[3] = __builtin_bit_cast(unsigned, p3) & mq.w;
                }
                const f16x8 a = __builtin_bit_cast(f16x8, au);
                __builtin_amdgcn_s_setprio(1);
                acc[f][0] = __builtin_amdgcn_mfma_f32_16x16x32_f16(a, b0, acc[f][0], 0, 0, 0);
                acc[f][1] = __builtin_amdgcn_mfma_f32_16x16x32_f16(a, b1, acc[f][1], 0, 0, 0);
                acc[f][2] = __builtin_amdgcn_mfma_f32_16x16x32_f16(a, b2, acc[f][2], 0, 0, 0);
                acc[f][3] = __builtin_amdgcn_mfma_f32_16x16x32_f16(a, b3, acc[f][3], 0, 0, 0);
                c5[f]     = __builtin_amdgcn_mfma_f32_16x16x32_f16(a, ones, c5[f], 0, 0, 0);
                __builtin_amdgcn_s_setprio(0);
            }
        }
        __syncthreads();   // stage/EG(t+1) landed; Bt[tile&1] free
    }

    const size_t so = (size_t)(slab * nh + h);
    #pragma unroll
    for (int f = 0; f < 4; ++f) {
        #pragma unroll
        for (int t4 = 0; t4 < 4; ++t4)
            #pragma unroll
            for (int r = 0; r < 4; ++r) {
                const int row = i0 + w * 64 + f * 16 + quad * 4 + r;
                num[(so * N_NODES + row) * D + t4 * 16 + li] = f2h(acc[f][t4][r]);
            }
        if (li == 0)
            #pragma unroll
            for (int r = 0; r < 4; ++r)
                den[so * N_NODES + i0 + w * 64 + f * 16 + quad * 4 + r] = c5[f][r];
    }
}

// ---------------------------------------------------------------- layer-1 combine fused into layer-2 GEMM, 4-way K-split (proven R13)
__global__ void __launch_bounds__(256) k_gemm2f(
    const short* __restrict__ num1, const float* __restrict__ den1,
    const float* __restrict__ cm1, const short* __restrict__ WoF,
    const float* __restrict__ av, const float* __restrict__ bv,
    short* __restrict__ WBout, float* __restrict__ fs, float* __restrict__ fd,
    unsigned* __restrict__ gmaxe, float* __restrict__ cm) {

    __shared__ __align__(16) float psum[3][64][16];   // waves 1..3 partial tiles
    __shared__ float csum[64];

    const int i0 = blockIdx.x * 16;            // 16 rows/block
    const int t = threadIdx.x, w = t >> 6, lane = t & 63;
    const int li = lane & 15, quad = lane >> 4, k0 = quad * 8;
    const int row = i0 + li;                   // A-row this lane owns

    // denominators for this wave's two heads
    float ds2[2];
    #pragma unroll
    for (int hh = 0; hh < 2; ++hh) {
        const int h = w * 2 + hh;
        float ds = 0.f;
        #pragma unroll
        for (int s = 0; s < S1; ++s)
            ds += den1[((size_t)s * H + h) * N_NODES + row];
        ds2[hh] = ds;
    }

    // build 4 A-fragments for k in [w*128, w*128+128)
    f16x8 afr[4];
    #pragma unroll
    for (int c = 0; c < 4; ++c) {
        const int col512 = w * 128 + c * 32 + k0;
        const int h   = col512 >> 6;
        const int col = col512 & 63;
        const int hh  = h - w * 2;             // 0 or 1
        float v8[8] = {0.f, 0.f, 0.f, 0.f, 0.f, 0.f, 0.f, 0.f};
        #pragma unroll
        for (int s = 0; s < S1; ++s) {
            bf16x8 nv = *(const bf16x8*)&num1[(((size_t)s * H + h) * N_NODES + row) * D + col];
            #pragma unroll
            for (int j = 0; j < 8; ++j) v8[j] += h2f((unsigned short)nv[j]);
        }
        const bool  uni  = !(ds2[hh] > 0.f);
        const float linv = uni ? 0.f : 1.f / ds2[hh];
        bf16x8 o;
        #pragma unroll
        for (int j = 0; j < 8; ++j) {
            float v = v8[j] * linv;
            if (uni) v = cm1[h * D + col + j];
            v = v > 0.f ? v : __expf(v) - 1.f;
            o[j] = f2h(v);
        }
        afr[c] = __builtin_bit_cast(f16x8, o);
    }

    // partial GEMM over this wave's K-quarter
    f32x4 c0 = {0.f, 0.f, 0.f, 0.f}, c1 = c0, c2 = c0, c3 = c0;
    #pragma unroll
    for (int c = 0; c < 4; ++c) {
        const int kt = w * 128 + c * 32;
        const f16x8 a = afr[c];
        const short* bb = WoF + (size_t)((kt >> 3) + quad) * (D * 8) + li * 8;
        f16x8 b0 = __builtin_bit_cast(f16x8, *(const bf16x8*)(bb));
        f16x8 b1 = __builtin_bit_cast(f16x8, *(const bf16x8*)(bb + 128));
        f16x8 b2 = __builtin_bit_cast(f16x8, *(const bf16x8*)(bb + 256));
        f16x8 b3 = __builtin_bit_cast(f16x8, *(const bf16x8*)(bb + 384));
        c0 = __builtin_amdgcn_mfma_f32_16x16x32_f16(a, b0, c0, 0, 0, 0);
        c1 = __builtin_amdgcn_mfma_f32_16x16x32_f16(a, b1, c1, 0, 0, 0);
        c2 = __builtin_amdgcn_mfma_f32_16x16x32_f16(a, b2, c2, 0, 0, 0);
        c3 = __builtin_amdgcn_mfma_f32_16x16x32_f16(a, b3, c3, 0, 0, 0);
    }

    // cross-wave reduce (intra-block): waves 1..3 park partials in LDS
    if (w > 0) {
        float* dst = &psum[w - 1][lane][0];
        #pragma unroll
        for (int r = 0; r < 4; ++r) {
            dst[r]      = c0[r];
            dst[4 + r]  = c1[r];
            dst[8 + r]  = c2[r];
            dst[12 + r] = c3[r];
        }
    }
    __syncthreads();
    if (w > 0) return;

    #pragma unroll
    for (int ww = 0; ww < 3; ++ww) {
        const float* src = &psum[ww][lane][0];
        #pragma unroll
        for (int r = 0; r < 4; ++r) {
            c0[r] += src[r];
            c1[r] += src[4 + r];
            c2[r] += src[8 + r];
            c3[r] += src[12 + r];
        }
    }

    // ---- epilogue (wave 0 only): WBout + fs/fd + gmax + colmean
    float av4[4], bv4[4];
    #pragma unroll
    for (int t4 = 0; t4 < 4; ++t4) {
        av4[t4] = av[t4 * 16 + li];
        bv4[t4] = bv[t4 * 16 + li];
    }
    float tiles[4][4];
    #pragma unroll
    for (int r = 0; r < 4; ++r) { tiles[0][r] = c0[r]; tiles[1][r] = c1[r]; tiles[2][r] = c2[r]; tiles[3][r] = c3[r]; }

    float fdmax = -INFINITY;
    float s4[4] = {0.f, 0.f, 0.f, 0.f};
    #pragma unroll
    for (int r = 0; r < 4; ++r) {
        const int orow = i0 + quad * 4 + r;
        float pa = 0.f, pb = 0.f;
        #pragma unroll
        for (int t4 = 0; t4 < 4; ++t4) {
            const float v = tiles[t4][r];
            const int d = t4 * 16 + li;
            WBout[((size_t)(orow >> 3)) * (D * 8) + d * 8 + (orow & 7)] = f2h(v);
            pa += v * av4[t4];
            pb += v * bv4[t4];
            s4[t4] += v;
        }
        #pragma unroll
        for (int off = 1; off < 16; off <<= 1) {
            pa += __shfl_xor(pa, off);
            pb += __shfl_xor(pb, off);
        }
        if (li == 0) {
            fs[orow] = pa;
            fd[orow] = pb;
        }
        fdmax = fmaxf(fdmax, pb);
    }
    fdmax = fmaxf(fdmax, __shfl_xor(fdmax, 16));
    fdmax = fmaxf(fdmax, __shfl_xor(fdmax, 32));
    if (lane == 0)
        atomicMax(gmaxe, fenc(fdmax));
    #pragma unroll
    for (int t4 = 0; t4 < 4; ++t4) {
        s4[t4] += __shfl_xor(s4[t4], 16);
        s4[t4] += __shfl_xor(s4[t4], 32);
    }
    if (quad == 0)
        #pragma unroll
        for (int t4 = 0; t4 < 4; ++t4) csum[t4 * 16 + li] = s4[t4];
    // csum written by quad-0 lanes, read by the same wave below (lgkm wait auto)
    if (lane < D)
        atomicAdd(&cm[lane], csum[lane] * (1.f / (float)N_NODES));
}

// ---------------------------------------------------------------- layer-2 combine (JS=S2) + ELU + log_softmax
__global__ void k_lsm(const short* __restrict__ num, const float* __restrict__ den,
                      const float* __restrict__ cm, float* __restrict__ out) {
    const int n    = blockIdx.x * 4 + (threadIdx.x >> 6);
    const int lane = threadIdx.x & 63;
    float v = 0.f, ds = 0.f;
    #pragma unroll
    for (int s = 0; s < S2; ++s)
        v += h2f((unsigned short)num[((size_t)s * N_NODES + n) * D + lane]);
    #pragma unroll
    for (int s = 0; s < S2; ++s) ds += den[(size_t)s * N_NODES + n];
    v = (ds > 0.f) ? v / ds : cm[lane];
    v = v > 0.f ? v : __expf(v) - 1.f;
    float mx = v;
    #pragma unroll
    for (int off = 32; off > 0; off >>= 1) mx = fmaxf(mx, __shfl_xor(mx, off));
    float ex = __expf(v - mx);
    float sum = ex;
    #pragma unroll
    for (int off = 32; off > 0; off >>= 1) sum += __shfl_xor(sum, off);
    out[(size_t)n * D + lane] = (v - mx) - __logf(sum);
}

// ----------------------------------------------------------------
extern "C" void kernel_launch(void* const* d_in, const int* in_sizes, int n_in,
                              void* d_out, int out_size, void* d_ws, size_t ws_size,
                              hipStream_t stream) {
    const float* x      = (const float*)d_in[0];
    const int*   adj    = (const int*)d_in[1];
    const float* W      = (const float*)d_in[2];
    const float* a_src  = (const float*)d_in[3];
    const float* a_dst  = (const float*)d_in[4];
    const float* W_o    = (const float*)d_in[5];
    const float* ao_src = (const float*)d_in[6];
    const float* ao_dst = (const float*)d_in[7];
    float* out = (float*)d_out;

    char* wsp = (char*)d_ws;
    size_t off = 0;
    auto alloc = [&](size_t bytes) -> void* {
        void* p = wsp + off;
        off += (bytes + 255) & ~(size_t)255;
        return p;
    };
    unsigned* adj_bits = (unsigned*)alloc((size_t)N_NODES * NWORDS * 8);
    short*    Xbf   = (short*)alloc((size_t)N_NODES * FDIM * 2);
    short*    WF1   = (short*)alloc((size_t)H * 64 * D * 8 * 2);
    short*    WoF   = (short*)alloc((size_t)64 * D * 8 * 2);
    short*    WhB   = (short*)alloc((size_t)H * N_NODES * D * 2);
    float*    fs1   = (float*)alloc((size_t)H * N_NODES * 4);
    float*    fd1   = (float*)alloc((size_t)H * N_NODES * 4);
    unsigned* gme1  = (unsigned*)alloc((size_t)H * 4);
    float*    cm1   = (float*)alloc((size_t)H * D * 4);
    short*    num1  = (short*)alloc((size_t)S1 * H * N_NODES * D * 2);
    float*    den1  = (float*)alloc((size_t)S1 * H * N_NODES * 4);
    short*    WhoB  = (short*)alloc((size_t)N_NODES * D * 2);
    float*    fs2   = (float*)alloc((size_t)N_NODES * 4);
    float*    fd2   = (float*)alloc((size_t)N_NODES * 4);
    unsigned* gme2  = (unsigned*)alloc(4);
    float*    cm2   = (float*)alloc((size_t)D * 4);
    short*    num2  = (short*)alloc((size_t)S2 * N_NODES * D * 2);
    float*    den2  = (float*)alloc((size_t)S2 * N_NODES * 4);

    k_pre  <<<dim3(1 + NB_BITS + NB_X + NB_W + NB_WO), dim3(256), 0, stream>>>(
        adj, x, W, W_o, adj_bits, Xbf, WF1, WoF, cm1, cm2, gme1, gme2);

    // layer 1 (8 heads)
    k_gemm <<<dim3(N_NODES / 64, H), dim3(256), 0, stream>>>(Xbf, WF1, a_src, a_dst,
                                                             WhB, fs1, fd1, gme1, cm1);
    k_accum<<<dim3(32 * H * S1), dim3(128), 0, stream>>>(adj_bits, WhB, fs1, fd1, gme1,
                                                         num1, den1, N_NODES / S1, H);

    // layer-1 combine fused into layer-2 GEMM (hcat never materialized)
    k_gemm2f<<<dim3(N_NODES / 16), dim3(256), 0, stream>>>(num1, den1, cm1, WoF,
                                                           ao_src, ao_dst,
                                                           WhoB, fs2, fd2, gme2, cm2);

    // layer 2 (single output head)
    k_accum<<<dim3(32 * S2), dim3(128), 0, stream>>>(adj_bits, WhoB, fs2, fd2, gme2,
                                                     num2, den2, N_NODES / S2, 1);
    k_lsm  <<<dim3(N_NODES / 4), dim3(256), 0, stream>>>(num2, den2, cm2, out);
}